// Round 11
// baseline (160.741 us; speedup 1.0000x reference)
//
#include <hip/hip_runtime.h>
#include <math.h>

// Fixed-point LeNet, B=2048. R20: FOUR waves per image.
// Evidence across R18/R19/R14: duration is monotone in resident waves
// (2048w/71.7us, 4096w/66.1us, 16384w/61us) with no pipe saturated
// (VALU<=40%, LDS~50%, HBM 16%) -> latency-bound, wave-starved. R19's cap
// was its own grid (2 waves/img). R20: block=256 = 4 waves/img, grid 2048
// -> 8192 waves = 8/SIMD potential; LDS 8.9KB, VGPR<=64 (launch_bounds 256,8).
// Phase A: wave wv does co = wv, wv+4, wv+8. Phase B: co = (t>>4)+16g.
// Phase C on wave 0. Bodies/fences/maps verbatim R19 (twice-verified).
//
// Output layout (fp32, concatenated flat in reference return order):
//   logp[2048,10], conv1_in[2048,784], conv1_out[2048,5760],
//   conv2_in[2048,1440], conv2_out[2048,1280], fc1_in[2048,320],
//   fc1_out[2048,50], fc2_in[2048,50], fc2_out[2048,10]

#define NB 2048

#define OFF_LOGP   0
#define OFF_C1IN   (OFF_LOGP  + NB*10)
#define OFF_C1OUT  (OFF_C1IN  + NB*784)
#define OFF_C2IN   (OFF_C1OUT + NB*5760)
#define OFF_C2OUT  (OFF_C2IN  + NB*1440)
#define OFF_FC1IN  (OFF_C2OUT + NB*1280)
#define OFF_FC1OUT (OFF_FC1IN + NB*320)
#define OFF_FC2IN  (OFF_FC1OUT+ NB*50)
#define OFF_FC2OUT (OFF_FC2IN + NB*50)

#define MAGIC_F 12582912.0f   // 1.5 * 2^23

// Workspace layout (floats): pre-quantized weights, written by k0_prep.
#define WS_WT1 0         // [320][64] transposed fw1: wT1[k*64+j]=clamp(quant(fw1[j][k])), j>=50 -> 0
#define WS_B1  20480     // [64]
#define WS_WT2 20544     // [50][16] transposed fw2: wT2[k*16+j], j>=10 -> 0
#define WS_B2  21344     // [16]
#define WS_CW2 21360     // [20*10][28] padded conv2 rows, quant(w)*256 (col>=25 -> 0)
#define WS_CB2 26960     // [20] quant(b)*256
#define WS_CW1 26980     // [10][28] padded conv1 rows, quant(w)*256
#define WS_CB1 27260     // [10] quant(b)*256   (total 27270 floats = 109 KB)

__device__ __forceinline__ float clamp8(float v) {
    return __builtin_amdgcn_fmed3f(v, -8.0f, 7.0f);
}

// ---------------- K0: weight pre-quantization (52 small blocks) ----------------
__global__ __launch_bounds__(256)
void k0_prep(const float* __restrict__ cw1, const float* __restrict__ cb1,
             const float* __restrict__ cw2, const float* __restrict__ cb2,
             const float* __restrict__ fw1, const float* __restrict__ fb1,
             const float* __restrict__ fw2, const float* __restrict__ fb2,
             float* __restrict__ ws)
{
    const int t = threadIdx.x, b = blockIdx.x;
    if (b < 50) {
        // wT1 row j=b: coalesced read fw1[b*320 + i], scattered (cheap) write.
        const float* src = fw1 + b * 320;
        for (int i = t; i < 320; i += 256)
            ws[WS_WT1 + i * 64 + b] = clamp8(rintf(src[i] * 256.0f) * (1.0f / 256.0f));
    } else if (b == 50) {
        for (int idx = t; idx < 320 * 14; idx += 256) {     // zero cols 50..63
            int i = idx / 14, j = 50 + idx % 14;
            ws[WS_WT1 + i * 64 + j] = 0.0f;
        }
        for (int idx = t; idx < 800; idx += 256) {          // wT2[50][16]
            int k = idx >> 4, j = idx & 15;
            ws[WS_WT2 + idx] = (j < 10) ? clamp8(rintf(fw2[j * 50 + k] * 256.0f) * (1.0f / 256.0f)) : 0.0f;
        }
        if (t < 64) ws[WS_B1 + t] = (t < 50) ? clamp8(rintf(fb1[t] * 256.0f) * (1.0f / 256.0f)) : 0.0f;
        if (t < 16) ws[WS_B2 + t] = (t < 10) ? clamp8(rintf(fb2[t] * 256.0f) * (1.0f / 256.0f)) : 0.0f;
    } else {   // b == 51: conv weights, padded [rows][28], x256
        for (int idx = t; idx < 5600; idx += 256) {
            int cc = idx / 28, col = idx % 28;
            ws[WS_CW2 + idx] = (col < 25) ? rintf(cw2[cc * 25 + col] * 256.0f) : 0.0f;
        }
        if (t < 20) ws[WS_CB2 + t] = rintf(cb2[t] * 256.0f);
        for (int idx = t; idx < 280; idx += 256) {
            int cc = idx / 28, col = idx % 28;
            ws[WS_CW1 + idx] = (col < 25) ? rintf(cw1[cc * 25 + col] * 256.0f) : 0.0f;
        }
        if (t >= 32 && t < 42) ws[WS_CB1 + (t - 32)] = rintf(cb1[t - 32] * 256.0f);
    }
}

// ---------------- K12W: whole net, FOUR waves per image ----------------
// block=256 (4 waves), grid = NB = 2048 -> 8192 waves = 8/SIMD potential.
// Phase A (conv1+pool1): lanes L<48: i=L>>1, jh=L&1; wave wv: co = wv,wv+4,wv+8.
// Phase B (conv2+pool2): co = (t>>4) + 16g, g=0,1 (t>>4 in 0..15; 2nd iter
//   only for t<64). ch=t&1, i2=(t>>1)&7; partners t^1, t^2 in-wave.
// Phase C (fc1+fc2+softmax): wave 0 only, k3 body verbatim.
// Conv weights read directly from ws (L1/L2-hot). 3 barriers.
__global__ __launch_bounds__(256, 8)
void k12w(const float* __restrict__ x, const float* __restrict__ ws,
          float* __restrict__ out)
{
    __shared__ __align__(16) float s_x[784];    // image; [0..320) reused as fc1in
    __shared__ __align__(16) float s_p1[1440];  // pool1 out = conv2 in

    const int t   = threadIdx.x;
    const int img = blockIdx.x;
    const int wv  = t >> 6;
    const int L   = t & 63;

    {   // input staging: quantize once, write c1in + LDS
        const float* xg = x + (size_t)img * 784;
        float* c1in_g = out + OFF_C1IN + (size_t)img * 784;
        for (int i = t; i < 784; i += 256) {
            float v = rintf(xg[i] * 256.0f) * (1.0f / 256.0f);
            s_x[i] = v;
            c1in_g[i] = v;
        }
    }
    __syncthreads();

    // ================= phase A: conv1 + pool1 (wave wv: co = wv + 4*c) =================
    if (L < 48) {
        const int i  = L >> 1;     // 0..23
        const int jh = L & 1;      // cols [12*jh, 12*jh+12)

        for (int co = wv; co < 10; co += 4) {
            asm volatile("" ::: "memory");   // block LICM: x-window reloads per co
            float wreg[28];
            {
                const float* wb = ws + WS_CW1 + co * 28;   // wave-uniform (L1-hot)
                #pragma unroll
                for (int k = 0; k < 7; k++) {
                    float4 v4 = *(const float4*)(wb + 4 * k);
                    wreg[4*k] = v4.x; wreg[4*k+1] = v4.y; wreg[4*k+2] = v4.z; wreg[4*k+3] = v4.w;
                }
            }
            float acc[12];
            #pragma unroll
            for (int j = 0; j < 12; j++) acc[j] = MAGIC_F;
            #pragma unroll
            for (int p = 0; p < 5; p++) {
                float xr[16];      // per-(co,p) reload — small live range
                const float* row = s_x + (i + p) * 28 + 12 * jh;
                #pragma unroll
                for (int k = 0; k < 4; k++) {
                    float4 v4 = *(const float4*)(row + 4 * k);
                    xr[4*k] = v4.x; xr[4*k+1] = v4.y; xr[4*k+2] = v4.z; xr[4*k+3] = v4.w;
                }
                #pragma unroll
                for (int q = 0; q < 5; q++) {
                    float w = wreg[p * 5 + q];
                    #pragma unroll
                    for (int j = 0; j < 12; j++)
                        acc[j] = fmaf(xr[q + j], w, acc[j]);   // mul+round+add
                }
            }
            const float C = MAGIC_F - ws[WS_CB1 + co];
            float v[12];
            #pragma unroll
            for (int j = 0; j < 12; j++) v[j] = (acc[j] - C) * (1.0f / 256.0f);

            float* gdst = out + OFF_C1OUT + (size_t)img * 5760 + co * 576 + i * 24 + 12 * jh;
            #pragma unroll
            for (int k = 0; k < 3; k++) {
                float4 st = { v[4*k], v[4*k+1], v[4*k+2], v[4*k+3] };
                *(float4*)(gdst + 4 * k) = st;
            }

            float m[6];
            #pragma unroll
            for (int j2 = 0; j2 < 6; j2++) m[j2] = fmaxf(v[2*j2], v[2*j2+1]);
            float pm[6];
            #pragma unroll
            for (int j2 = 0; j2 < 6; j2++) pm[j2] = __shfl_xor(m[j2], 2);  // partner i^1

            if ((i & 1) == 0) {
                float pr[6];
                #pragma unroll
                for (int j2 = 0; j2 < 6; j2++)
                    pr[j2] = fmaxf(fmaxf(m[j2], pm[j2]), 0.0f);
                const int o = co * 144 + (i >> 1) * 12 + 6 * jh;
                float* g = out + OFF_C2IN + (size_t)img * 1440 + o;
                #pragma unroll
                for (int k = 0; k < 3; k++) {
                    float2 st = { pr[2*k], pr[2*k+1] };
                    *(float2*)(g + 2 * k) = st;
                    *(float2*)(s_p1 + o + 2 * k) = st;    // LDS handoff
                }
            }
        }
    }
    __syncthreads();   // s_p1 complete (all 10 ci)

    // ================= phase B: conv2 + pool2 (co = (t>>4) + 16g) =================
    const int ch = t & 1;              // ci-half
    const int i2 = (t >> 1) & 7;

    auto conv2_body = [&](int co) {
        float acc[8];
        #pragma unroll
        for (int j = 0; j < 8; j++) acc[j] = MAGIC_F;

        #pragma unroll
        for (int cc = 0; cc < 5; cc++) {
            const int ci = ch * 5 + cc;
            float wreg[28];
            {
                const float* wb = ws + WS_CW2 + (co * 10 + ci) * 28;   // L1-hot
                #pragma unroll
                for (int k = 0; k < 7; k++) {
                    float4 v4 = *(const float4*)(wb + 4 * k);
                    wreg[4*k] = v4.x; wreg[4*k+1] = v4.y; wreg[4*k+2] = v4.z; wreg[4*k+3] = v4.w;
                }
            }
            const float* xb = s_p1 + ci * 144;
            #pragma unroll
            for (int p = 0; p < 5; p++) {
                const float* row = xb + (i2 + p) * 12;
                float4 a4 = *(const float4*)(row);
                float4 b4 = *(const float4*)(row + 4);
                float4 c4 = *(const float4*)(row + 8);
                float xr[12] = { a4.x, a4.y, a4.z, a4.w, b4.x, b4.y, b4.z, b4.w,
                                 c4.x, c4.y, c4.z, c4.w };
                #pragma unroll
                for (int q = 0; q < 5; q++) {
                    float w = wreg[p * 5 + q];
                    #pragma unroll
                    for (int j = 0; j < 8; j++)
                        acc[j] = fmaf(xr[q + j], w, acc[j]);
                }
            }
        }

        float s[8];
        #pragma unroll
        for (int j = 0; j < 8; j++) s[j] = acc[j] - MAGIC_F;       // exact un-bias
        #pragma unroll
        for (int j = 0; j < 8; j++) s[j] += __shfl_xor(s[j], 1);   // other ci-half

        const float b2 = ws[WS_CB2 + co];
        float v[8];
        #pragma unroll
        for (int j = 0; j < 8; j++) v[j] = (s[j] + b2) * (1.0f / 256.0f);

        float m[4], pm[4];
        #pragma unroll
        for (int c = 0; c < 4; c++) m[c] = fmaxf(v[2*c], v[2*c+1]);
        #pragma unroll
        for (int c = 0; c < 4; c++) pm[c] = __shfl_xor(m[c], 2);   // partner i^1

        if (ch == 0) {
            float4 st0 = { v[0], v[1], v[2], v[3] };
            float4 st1 = { v[4], v[5], v[6], v[7] };
            float* cdst = out + OFF_C2OUT + (size_t)img * 1280 + co * 64 + i2 * 8;
            *(float4*)(cdst)     = st0;
            *(float4*)(cdst + 4) = st1;

            if ((i2 & 1) == 0) {
                float4 pr = { fmaxf(fmaxf(m[0], pm[0]), 0.0f),
                              fmaxf(fmaxf(m[1], pm[1]), 0.0f),
                              fmaxf(fmaxf(m[2], pm[2]), 0.0f),
                              fmaxf(fmaxf(m[3], pm[3]), 0.0f) };
                const int o = co * 16 + (i2 >> 1) * 4;
                *(float4*)(out + OFF_FC1IN + (size_t)img * 320 + o) = pr;
                float4 prc = { clamp8(pr.x), clamp8(pr.y), clamp8(pr.z), clamp8(pr.w) };
                *(float4*)(s_x + o) = prc;            // clamped fc1 input (x dead)
            }
        }
    };

    for (int co0 = t >> 4; co0 < 20; co0 += 16) {
        asm volatile("" ::: "memory");   // block LICM across iterations
        conv2_body(co0);                 // co 0..15 all threads; 16..19 on t<64
    }
    __syncthreads();   // fc1in (s_x[0..320)) complete

    // ================= phase C: fc1 + fc2 + log_softmax (wave 0 only) =================
    if (wv == 0) {
        const float* sf = s_x;
        float acc = ws[WS_B1 + L];
        #pragma unroll 8
        for (int k = 0; k < 320; k++)
            acc = fmaf(sf[k], ws[WS_WT1 + k * 64 + L], acc);   // LDS broadcast + 256B coalesced
        float o1 = rintf(clamp8(acc) * 256.0f) * (1.0f / 256.0f);
        float r1 = fmaxf(o1, 0.0f);
        if (L < 50) {
            out[OFF_FC1OUT + (size_t)img * 50 + L] = o1;
            out[OFF_FC2IN  + (size_t)img * 50 + L] = r1;
        }
        float yc = clamp8(r1);                 // valid on lanes 0..49

        float acc2 = ws[WS_B2 + (L & 15)];
        #pragma unroll 10
        for (int k = 0; k < 50; k++) {
            float yk = __shfl(yc, k);
            acc2 = fmaf(yk, ws[WS_WT2 + k * 16 + (L & 15)], acc2);
        }
        float o2 = rintf(clamp8(acc2) * 256.0f) * (1.0f / 256.0f);
        if (L < 10) out[OFF_FC2OUT + (size_t)img * 10 + L] = o2;

        float vmx = (L < 10) ? o2 : -3.0e38f;
        #pragma unroll
        for (int d = 1; d < 16; d <<= 1)
            vmx = fmaxf(vmx, __shfl_xor(vmx, d, 16));
        float e = (L < 10) ? expf(o2 - vmx) : 0.0f;
        #pragma unroll
        for (int d = 1; d < 16; d <<= 1)
            e += __shfl_xor(e, d, 16);
        float lse = vmx + logf(e);
        if (L < 10) out[OFF_LOGP + (size_t)img * 10 + L] = o2 - lse;
    }
}

extern "C" void kernel_launch(void* const* d_in, const int* in_sizes, int n_in,
                              void* d_out, int out_size, void* d_ws, size_t ws_size,
                              hipStream_t stream) {
    const float* x   = (const float*)d_in[0];
    const float* cw1 = (const float*)d_in[1];
    const float* cb1 = (const float*)d_in[2];
    const float* cw2 = (const float*)d_in[3];
    const float* cb2 = (const float*)d_in[4];
    const float* fw1 = (const float*)d_in[5];
    const float* fb1 = (const float*)d_in[6];
    const float* fw2 = (const float*)d_in[7];
    const float* fb2 = (const float*)d_in[8];
    float* o  = (float*)d_out;
    float* ws = (float*)d_ws;

    k0_prep<<<52, 256, 0, stream>>>(cw1, cb1, cw2, cb2, fw1, fb1, fw2, fb2, ws);
    k12w   <<<NB, 256, 0, stream>>>(x, ws, o);
}

// Round 12
// 153.409 us; speedup vs baseline: 1.0478x; 1.0478x over previous
//
#include <hip/hip_runtime.h>
#include <math.h>

// Fixed-point LeNet, B=2048. R21: R20 + conflict-free conv1 map.
// R20 post-mortem: occupancy 31->56% with dur flat -> wave-starvation over;
// LDS pipe is the loaded resource (~62% busy), and 1.016e7 conflict-cycles
// (4.9k/block, constant since R19) are conv1 x-reads (rows i,i+8,i+16 alias:
// 8*28 = 0 mod 32; any float4 stride does this with 24 rows/wave).
// Fix INSIDE the 4-wave structure (R15's remap needed a barrier; this doesn't):
// wave wv owns 6 consecutive rows i=6wv..6wv+5; lane = c5*12 + ii*2 + jh
// (60 active); loop h=0,1: co=5h+c5. Per instruction: 6 distinct rows ->
// bank offsets {0,28,24,20,16,12}(+12jh) -> max 2-way = free. Pool partner
// still lane^2. 8 balanced co-iters vs 10 unbalanced. Bit-identical math.
// Phase B / C / k0_prep verbatim R20.
//
// Output layout (fp32, concatenated flat in reference return order):
//   logp[2048,10], conv1_in[2048,784], conv1_out[2048,5760],
//   conv2_in[2048,1440], conv2_out[2048,1280], fc1_in[2048,320],
//   fc1_out[2048,50], fc2_in[2048,50], fc2_out[2048,10]

#define NB 2048

#define OFF_LOGP   0
#define OFF_C1IN   (OFF_LOGP  + NB*10)
#define OFF_C1OUT  (OFF_C1IN  + NB*784)
#define OFF_C2IN   (OFF_C1OUT + NB*5760)
#define OFF_C2OUT  (OFF_C2IN  + NB*1440)
#define OFF_FC1IN  (OFF_C2OUT + NB*1280)
#define OFF_FC1OUT (OFF_FC1IN + NB*320)
#define OFF_FC2IN  (OFF_FC1OUT+ NB*50)
#define OFF_FC2OUT (OFF_FC2IN + NB*50)

#define MAGIC_F 12582912.0f   // 1.5 * 2^23

// Workspace layout (floats): pre-quantized weights, written by k0_prep.
#define WS_WT1 0         // [320][64] transposed fw1: wT1[k*64+j]=clamp(quant(fw1[j][k])), j>=50 -> 0
#define WS_B1  20480     // [64]
#define WS_WT2 20544     // [50][16] transposed fw2: wT2[k*16+j], j>=10 -> 0
#define WS_B2  21344     // [16]
#define WS_CW2 21360     // [20*10][28] padded conv2 rows, quant(w)*256 (col>=25 -> 0)
#define WS_CB2 26960     // [20] quant(b)*256
#define WS_CW1 26980     // [10][28] padded conv1 rows, quant(w)*256
#define WS_CB1 27260     // [10] quant(b)*256   (total 27270 floats = 109 KB)

__device__ __forceinline__ float clamp8(float v) {
    return __builtin_amdgcn_fmed3f(v, -8.0f, 7.0f);
}

// ---------------- K0: weight pre-quantization (52 small blocks) ----------------
__global__ __launch_bounds__(256)
void k0_prep(const float* __restrict__ cw1, const float* __restrict__ cb1,
             const float* __restrict__ cw2, const float* __restrict__ cb2,
             const float* __restrict__ fw1, const float* __restrict__ fb1,
             const float* __restrict__ fw2, const float* __restrict__ fb2,
             float* __restrict__ ws)
{
    const int t = threadIdx.x, b = blockIdx.x;
    if (b < 50) {
        // wT1 row j=b: coalesced read fw1[b*320 + i], scattered (cheap) write.
        const float* src = fw1 + b * 320;
        for (int i = t; i < 320; i += 256)
            ws[WS_WT1 + i * 64 + b] = clamp8(rintf(src[i] * 256.0f) * (1.0f / 256.0f));
    } else if (b == 50) {
        for (int idx = t; idx < 320 * 14; idx += 256) {     // zero cols 50..63
            int i = idx / 14, j = 50 + idx % 14;
            ws[WS_WT1 + i * 64 + j] = 0.0f;
        }
        for (int idx = t; idx < 800; idx += 256) {          // wT2[50][16]
            int k = idx >> 4, j = idx & 15;
            ws[WS_WT2 + idx] = (j < 10) ? clamp8(rintf(fw2[j * 50 + k] * 256.0f) * (1.0f / 256.0f)) : 0.0f;
        }
        if (t < 64) ws[WS_B1 + t] = (t < 50) ? clamp8(rintf(fb1[t] * 256.0f) * (1.0f / 256.0f)) : 0.0f;
        if (t < 16) ws[WS_B2 + t] = (t < 10) ? clamp8(rintf(fb2[t] * 256.0f) * (1.0f / 256.0f)) : 0.0f;
    } else {   // b == 51: conv weights, padded [rows][28], x256
        for (int idx = t; idx < 5600; idx += 256) {
            int cc = idx / 28, col = idx % 28;
            ws[WS_CW2 + idx] = (col < 25) ? rintf(cw2[cc * 25 + col] * 256.0f) : 0.0f;
        }
        if (t < 20) ws[WS_CB2 + t] = rintf(cb2[t] * 256.0f);
        for (int idx = t; idx < 280; idx += 256) {
            int cc = idx / 28, col = idx % 28;
            ws[WS_CW1 + idx] = (col < 25) ? rintf(cw1[cc * 25 + col] * 256.0f) : 0.0f;
        }
        if (t >= 32 && t < 42) ws[WS_CB1 + (t - 32)] = rintf(cb1[t - 32] * 256.0f);
    }
}

// ---------------- K12W: whole net, FOUR waves per image ----------------
// block=256 (4 waves), grid = NB = 2048 -> 8192 waves.
// Phase A (conv1+pool1): wave wv owns rows i=6wv..6wv+5. Lane (L<60):
//   c5=L/12, r=L%12, ii=r>>1, jh=r&1, i=6wv+ii; loop h=0,1: co=5h+c5.
//   Conflict-free (6 rows -> 2-way max); pool partner = lane L^2.
// Phase B (conv2+pool2): co = (t>>4) + 16g, g=0,1 (2nd iter t<64).
//   ch=t&1, i2=(t>>1)&7; partners t^1, t^2 in-wave.
// Phase C (fc1+fc2+softmax): wave 0 only.
__global__ __launch_bounds__(256, 8)
void k12w(const float* __restrict__ x, const float* __restrict__ ws,
          float* __restrict__ out)
{
    __shared__ __align__(16) float s_x[784];    // image; [0..320) reused as fc1in
    __shared__ __align__(16) float s_p1[1440];  // pool1 out = conv2 in

    const int t   = threadIdx.x;
    const int img = blockIdx.x;
    const int wv  = t >> 6;
    const int L   = t & 63;

    {   // input staging: quantize once, write c1in + LDS
        const float* xg = x + (size_t)img * 784;
        float* c1in_g = out + OFF_C1IN + (size_t)img * 784;
        for (int i = t; i < 784; i += 256) {
            float v = rintf(xg[i] * 256.0f) * (1.0f / 256.0f);
            s_x[i] = v;
            c1in_g[i] = v;
        }
    }
    __syncthreads();

    // ================= phase A: conv1 + pool1 (6 consecutive rows per wave) =================
    if (L < 60) {
        const int c5 = L / 12;         // 0..4: co column within half
        const int r  = L % 12;
        const int ii = r >> 1;         // 0..5
        const int jh = r & 1;          // cols [12*jh, 12*jh+12)
        const int i  = wv * 6 + ii;    // 0..23; wave-local rows consecutive

        for (int h = 0; h < 2; h++) {
            asm volatile("" ::: "memory");   // block LICM: x-window reloads per co
            const int co = h * 5 + c5;
            float wreg[28];
            {
                const float* wb = ws + WS_CW1 + co * 28;   // L1-hot, 12-lane broadcast
                #pragma unroll
                for (int k = 0; k < 7; k++) {
                    float4 v4 = *(const float4*)(wb + 4 * k);
                    wreg[4*k] = v4.x; wreg[4*k+1] = v4.y; wreg[4*k+2] = v4.z; wreg[4*k+3] = v4.w;
                }
            }
            float acc[12];
            #pragma unroll
            for (int j = 0; j < 12; j++) acc[j] = MAGIC_F;
            #pragma unroll
            for (int p = 0; p < 5; p++) {
                float xr[16];      // per-(co,p) reload — small live range
                const float* row = s_x + (i + p) * 28 + 12 * jh;
                #pragma unroll
                for (int k = 0; k < 4; k++) {
                    float4 v4 = *(const float4*)(row + 4 * k);
                    xr[4*k] = v4.x; xr[4*k+1] = v4.y; xr[4*k+2] = v4.z; xr[4*k+3] = v4.w;
                }
                #pragma unroll
                for (int q = 0; q < 5; q++) {
                    float w = wreg[p * 5 + q];
                    #pragma unroll
                    for (int j = 0; j < 12; j++)
                        acc[j] = fmaf(xr[q + j], w, acc[j]);   // mul+round+add
                }
            }
            const float C = MAGIC_F - ws[WS_CB1 + co];
            float v[12];
            #pragma unroll
            for (int j = 0; j < 12; j++) v[j] = (acc[j] - C) * (1.0f / 256.0f);

            float* gdst = out + OFF_C1OUT + (size_t)img * 5760 + co * 576 + i * 24 + 12 * jh;
            #pragma unroll
            for (int k = 0; k < 3; k++) {
                float4 st = { v[4*k], v[4*k+1], v[4*k+2], v[4*k+3] };
                *(float4*)(gdst + 4 * k) = st;
            }

            float m[6];
            #pragma unroll
            for (int j2 = 0; j2 < 6; j2++) m[j2] = fmaxf(v[2*j2], v[2*j2+1]);
            float pm[6];
            #pragma unroll
            for (int j2 = 0; j2 < 6; j2++) pm[j2] = __shfl_xor(m[j2], 2);  // partner i^1

            if ((ii & 1) == 0) {
                float pr[6];
                #pragma unroll
                for (int j2 = 0; j2 < 6; j2++)
                    pr[j2] = fmaxf(fmaxf(m[j2], pm[j2]), 0.0f);
                const int o = co * 144 + (i >> 1) * 12 + 6 * jh;
                float* g = out + OFF_C2IN + (size_t)img * 1440 + o;
                #pragma unroll
                for (int k = 0; k < 3; k++) {
                    float2 st = { pr[2*k], pr[2*k+1] };
                    *(float2*)(g + 2 * k) = st;
                    *(float2*)(s_p1 + o + 2 * k) = st;    // LDS handoff
                }
            }
        }
    }
    __syncthreads();   // s_p1 complete (all 10 ci)

    // ================= phase B: conv2 + pool2 (co = (t>>4) + 16g) =================
    const int ch = t & 1;              // ci-half
    const int i2 = (t >> 1) & 7;

    auto conv2_body = [&](int co) {
        float acc[8];
        #pragma unroll
        for (int j = 0; j < 8; j++) acc[j] = MAGIC_F;

        #pragma unroll
        for (int cc = 0; cc < 5; cc++) {
            const int ci = ch * 5 + cc;
            float wreg[28];
            {
                const float* wb = ws + WS_CW2 + (co * 10 + ci) * 28;   // L1-hot
                #pragma unroll
                for (int k = 0; k < 7; k++) {
                    float4 v4 = *(const float4*)(wb + 4 * k);
                    wreg[4*k] = v4.x; wreg[4*k+1] = v4.y; wreg[4*k+2] = v4.z; wreg[4*k+3] = v4.w;
                }
            }
            const float* xb = s_p1 + ci * 144;
            #pragma unroll
            for (int p = 0; p < 5; p++) {
                const float* row = xb + (i2 + p) * 12;
                float4 a4 = *(const float4*)(row);
                float4 b4 = *(const float4*)(row + 4);
                float4 c4 = *(const float4*)(row + 8);
                float xr[12] = { a4.x, a4.y, a4.z, a4.w, b4.x, b4.y, b4.z, b4.w,
                                 c4.x, c4.y, c4.z, c4.w };
                #pragma unroll
                for (int q = 0; q < 5; q++) {
                    float w = wreg[p * 5 + q];
                    #pragma unroll
                    for (int j = 0; j < 8; j++)
                        acc[j] = fmaf(xr[q + j], w, acc[j]);
                }
            }
        }

        float s[8];
        #pragma unroll
        for (int j = 0; j < 8; j++) s[j] = acc[j] - MAGIC_F;       // exact un-bias
        #pragma unroll
        for (int j = 0; j < 8; j++) s[j] += __shfl_xor(s[j], 1);   // other ci-half

        const float b2 = ws[WS_CB2 + co];
        float v[8];
        #pragma unroll
        for (int j = 0; j < 8; j++) v[j] = (s[j] + b2) * (1.0f / 256.0f);

        float m[4], pm[4];
        #pragma unroll
        for (int c = 0; c < 4; c++) m[c] = fmaxf(v[2*c], v[2*c+1]);
        #pragma unroll
        for (int c = 0; c < 4; c++) pm[c] = __shfl_xor(m[c], 2);   // partner i^1

        if (ch == 0) {
            float4 st0 = { v[0], v[1], v[2], v[3] };
            float4 st1 = { v[4], v[5], v[6], v[7] };
            float* cdst = out + OFF_C2OUT + (size_t)img * 1280 + co * 64 + i2 * 8;
            *(float4*)(cdst)     = st0;
            *(float4*)(cdst + 4) = st1;

            if ((i2 & 1) == 0) {
                float4 pr = { fmaxf(fmaxf(m[0], pm[0]), 0.0f),
                              fmaxf(fmaxf(m[1], pm[1]), 0.0f),
                              fmaxf(fmaxf(m[2], pm[2]), 0.0f),
                              fmaxf(fmaxf(m[3], pm[3]), 0.0f) };
                const int o = co * 16 + (i2 >> 1) * 4;
                *(float4*)(out + OFF_FC1IN + (size_t)img * 320 + o) = pr;
                float4 prc = { clamp8(pr.x), clamp8(pr.y), clamp8(pr.z), clamp8(pr.w) };
                *(float4*)(s_x + o) = prc;            // clamped fc1 input (x dead)
            }
        }
    };

    for (int co0 = t >> 4; co0 < 20; co0 += 16) {
        asm volatile("" ::: "memory");   // block LICM across iterations
        conv2_body(co0);                 // co 0..15 all threads; 16..19 on t<64
    }
    __syncthreads();   // fc1in (s_x[0..320)) complete

    // ================= phase C: fc1 + fc2 + log_softmax (wave 0 only) =================
    if (wv == 0) {
        const float* sf = s_x;
        float acc = ws[WS_B1 + L];
        #pragma unroll 8
        for (int k = 0; k < 320; k++)
            acc = fmaf(sf[k], ws[WS_WT1 + k * 64 + L], acc);   // LDS broadcast + 256B coalesced
        float o1 = rintf(clamp8(acc) * 256.0f) * (1.0f / 256.0f);
        float r1 = fmaxf(o1, 0.0f);
        if (L < 50) {
            out[OFF_FC1OUT + (size_t)img * 50 + L] = o1;
            out[OFF_FC2IN  + (size_t)img * 50 + L] = r1;
        }
        float yc = clamp8(r1);                 // valid on lanes 0..49

        float acc2 = ws[WS_B2 + (L & 15)];
        #pragma unroll 10
        for (int k = 0; k < 50; k++) {
            float yk = __shfl(yc, k);
            acc2 = fmaf(yk, ws[WS_WT2 + k * 16 + (L & 15)], acc2);
        }
        float o2 = rintf(clamp8(acc2) * 256.0f) * (1.0f / 256.0f);
        if (L < 10) out[OFF_FC2OUT + (size_t)img * 10 + L] = o2;

        float vmx = (L < 10) ? o2 : -3.0e38f;
        #pragma unroll
        for (int d = 1; d < 16; d <<= 1)
            vmx = fmaxf(vmx, __shfl_xor(vmx, d, 16));
        float e = (L < 10) ? expf(o2 - vmx) : 0.0f;
        #pragma unroll
        for (int d = 1; d < 16; d <<= 1)
            e += __shfl_xor(e, d, 16);
        float lse = vmx + logf(e);
        if (L < 10) out[OFF_LOGP + (size_t)img * 10 + L] = o2 - lse;
    }
}

extern "C" void kernel_launch(void* const* d_in, const int* in_sizes, int n_in,
                              void* d_out, int out_size, void* d_ws, size_t ws_size,
                              hipStream_t stream) {
    const float* x   = (const float*)d_in[0];
    const float* cw1 = (const float*)d_in[1];
    const float* cb1 = (const float*)d_in[2];
    const float* cw2 = (const float*)d_in[3];
    const float* cb2 = (const float*)d_in[4];
    const float* fw1 = (const float*)d_in[5];
    const float* fb1 = (const float*)d_in[6];
    const float* fw2 = (const float*)d_in[7];
    const float* fb2 = (const float*)d_in[8];
    float* o  = (float*)d_out;
    float* ws = (float*)d_ws;

    k0_prep<<<52, 256, 0, stream>>>(cw1, cb1, cw2, cb2, fw1, fb1, fw2, fb2, ws);
    k12w   <<<NB, 256, 0, stream>>>(x, ws, o);
}